// Round 4
// baseline (17570.441 us; speedup 1.0000x reference)
//
#include <hip/hip_runtime.h>
#include <math.h>

// ConditionalFlow — deliberately vanilla fp32 baseline (diagnostic round).
// 6 RealNVP coupling layers fused in ONE kernel; block = 16 rows, owned
// exclusively across all layers. No MFMA / no async-LDS / no fp16 / no ws.

#define DIMX 256
#define CTXD 256
#define HIDD 1024
#define NLAY 6
#define NB   65536
#define INF  384            // 128 masked + 256 context
#define ROWS 16

__global__ __launch_bounds__(256) void flow_naive_k(
    const float* __restrict__ x_in, const float* __restrict__ ctxg,
    const float* __restrict__ W1g, const float* __restrict__ b1g,
    const float* __restrict__ W2g, const float* __restrict__ b2g,
    float* __restrict__ out) {
  __shared__ float stin[ROWS][INF + 1];   // 24.6 KB
  __shared__ float hbuf[ROWS][65];        //  4.2 KB
  __shared__ float ldp[ROWS][17];         //  1.1 KB

  const int tid  = threadIdx.x;           // 256 threads
  const int row0 = blockIdx.x * ROWS;     // 4096 blocks

  float* xout  = out;                       // [B][256] working/output x
  float* ldout = out + (size_t)NB * DIMX;   // [B] log_det

  const int r_own = tid & 15;             // row for GEMM2 / epilogue
  const int cg    = tid >> 4;             // col-group 0..15
  const int hc    = tid & 63;             // GEMM1: h col within chunk
  const int r0    = (tid >> 6) * 4;       // GEMM1: first of 4 rows

  float ldacc = 0.0f;

  for (int i = 0; i < NLAY; i++) {
    const int p = i & 1;
    const float* xm_src = (i == 0) ? x_in : xout;  // masked cols written at i-1
    const float* xu_src = (i <= 1) ? x_in : xout;  // updated cols written at i-2

    // ---- stage st_in = [x_m | context] (16 x 384) into LDS
    for (int idx = tid; idx < ROWS * INF; idx += 256) {
      int r = idx / INF;
      int c = idx - r * INF;
      float v;
      if (c < 128) v = xm_src[(size_t)(row0 + r) * DIMX + 2 * c + p];
      else         v = ctxg[(size_t)(row0 + r) * CTXD + (c - 128)];
      stin[r][c] = v;
    }
    __syncthreads();

    // ---- st accumulators: thread owns (row r_own, cols j*16+cg, j=0..15)
    float st[16];
#pragma unroll
    for (int j = 0; j < 16; j++) st[j] = 0.0f;

    for (int c = 0; c < 16; c++) {        // HID chunks of 64
      // GEMM1: h[r0..r0+3][hc] = relu(sum_k stin[r][k] * W1[k][c*64+hc] + b1)
      float acc0 = 0.f, acc1 = 0.f, acc2 = 0.f, acc3 = 0.f;
      const float* w1p = W1g + (size_t)i * INF * HIDD + c * 64 + hc;
      for (int k = 0; k < INF; k++) {
        float wv = w1p[(size_t)k * HIDD];        // 64 lanes: 256B coalesced
        acc0 += stin[r0 + 0][k] * wv;            // LDS broadcast reads
        acc1 += stin[r0 + 1][k] * wv;
        acc2 += stin[r0 + 2][k] * wv;
        acc3 += stin[r0 + 3][k] * wv;
      }
      float b1v = b1g[(size_t)i * HIDD + c * 64 + hc];
      acc0 += b1v; acc1 += b1v; acc2 += b1v; acc3 += b1v;
      __syncthreads();                    // prev chunk's GEMM2 done with hbuf
      hbuf[r0 + 0][hc] = acc0 > 0.f ? acc0 : 0.f;
      hbuf[r0 + 1][hc] = acc1 > 0.f ? acc1 : 0.f;
      hbuf[r0 + 2][hc] = acc2 > 0.f ? acc2 : 0.f;
      hbuf[r0 + 3][hc] = acc3 > 0.f ? acc3 : 0.f;
      __syncthreads();                    // hbuf ready

      // GEMM2: st[j] += sum_k hbuf[r_own][k] * W2[c*64+k][j*16+cg]
      const float* w2p = W2g + ((size_t)i * HIDD + c * 64) * DIMX + cg;
      for (int k = 0; k < 64; k++) {
        float hv = hbuf[r_own][k];
        const float* w2row = w2p + (size_t)k * DIMX;
#pragma unroll
        for (int j = 0; j < 16; j++)
          st[j] += hv * w2row[j * 16];    // 4 distinct addrs/wave, L1 broadcast
      }
    }

    // ---- epilogue: s = 5*tanh(st_s + b2s); y = x_u * exp(s) + (st_t + b2t)
#pragma unroll
    for (int j = 0; j < 8; j++) {
      int   col  = j * 16 + cg;                        // s col 0..127
      float b2s  = b2g[(size_t)i * DIMX + col];
      float b2t  = b2g[(size_t)i * DIMX + 128 + col];
      float s    = 5.0f * tanhf(st[j] + b2s);
      float tt   = st[j + 8] + b2t;
      ldacc     += s;
      int   colu = 2 * col + 1 - p;                    // updated x col
      size_t row = (size_t)(row0 + r_own);
      float xu   = xu_src[row * DIMX + colu];
      xout[row * DIMX + colu] = xu * expf(s) + tt;
    }
    __syncthreads();   // y-stores visible before next layer's stin load
  }

  // ---- log_det: reduce the 16 col-groups per row
  ldp[r_own][cg] = ldacc;
  __syncthreads();
  if (tid < ROWS) {
    float s = 0.0f;
#pragma unroll
    for (int c = 0; c < 16; c++) s += ldp[tid][c];
    ldout[row0 + tid] = s;
  }
}

extern "C" void kernel_launch(void* const* d_in, const int* in_sizes, int n_in,
                              void* d_out, int out_size, void* d_ws, size_t ws_size,
                              hipStream_t stream) {
  (void)in_sizes; (void)n_in; (void)out_size; (void)d_ws; (void)ws_size;
  const float* x   = (const float*)d_in[0];
  const float* ctx = (const float*)d_in[1];
  const float* W1  = (const float*)d_in[2];
  const float* b1  = (const float*)d_in[3];
  const float* W2  = (const float*)d_in[4];
  const float* b2  = (const float*)d_in[5];
  float* out = (float*)d_out;

  flow_naive_k<<<dim3(NB / ROWS), dim3(256), 0, stream>>>(
      x, ctx, W1, b1, W2, b2, out);
}